// Round 1
// baseline (540.086 us; speedup 1.0000x reference)
//
#include <hip/hip_runtime.h>
#include <math.h>

#define BB 16
#define SS 4096
#define HH 1024
#define CC 64

// ---------------- Kernel A: scores[b][c][s] = sum_h hidden[b,s,h] * querys[c,h]
// 64(s) x 64(c) tile per block, K-chunks of 64 over H. LDS tiles stored k-major
// so the inner loop does 2x ds_read_b128 + 16 FMA per lane.
__global__ __launch_bounds__(256) void scores_kernel(
    const float* __restrict__ hidden, const float* __restrict__ querys,
    float* __restrict__ scores)
{
    const int b  = blockIdx.y;
    const int s0 = blockIdx.x * 64;
    const int t  = threadIdx.x;
    const int tx = t & 15;        // c-quad
    const int ty = t >> 4;        // s-quad
    const int lr  = t >> 4;       // load row 0..15
    const int lk4 = (t & 15) * 4; // load col 0..60

    __shared__ float hs[64][68];  // [k][s]
    __shared__ float qs[64][68];  // [k][c]

    float acc[4][4];
#pragma unroll
    for (int i = 0; i < 4; ++i)
#pragma unroll
        for (int j = 0; j < 4; ++j) acc[i][j] = 0.0f;

    for (int k0 = 0; k0 < HH; k0 += 64) {
#pragma unroll
        for (int rr = 0; rr < 4; ++rr) {
            const int r = lr + rr * 16;
            const float4 v = *(const float4*)&hidden[((size_t)b * SS + (size_t)(s0 + r)) * HH + k0 + lk4];
            hs[lk4 + 0][r] = v.x; hs[lk4 + 1][r] = v.y;
            hs[lk4 + 2][r] = v.z; hs[lk4 + 3][r] = v.w;
        }
#pragma unroll
        for (int rr = 0; rr < 4; ++rr) {
            const int c = lr + rr * 16;
            const float4 v = *(const float4*)&querys[(size_t)c * HH + k0 + lk4];
            qs[lk4 + 0][c] = v.x; qs[lk4 + 1][c] = v.y;
            qs[lk4 + 2][c] = v.z; qs[lk4 + 3][c] = v.w;
        }
        __syncthreads();
#pragma unroll 8
        for (int k = 0; k < 64; ++k) {
            const float4 a = *(const float4*)&hs[k][ty * 4];
            const float4 q = *(const float4*)&qs[k][tx * 4];
            const float av[4] = {a.x, a.y, a.z, a.w};
            const float qv[4] = {q.x, q.y, q.z, q.w};
#pragma unroll
            for (int i = 0; i < 4; ++i)
#pragma unroll
                for (int j = 0; j < 4; ++j)
                    acc[i][j] = fmaf(av[i], qv[j], acc[i][j]);
        }
        __syncthreads();
    }
    // store scores[b][c][s], c = tx*4+j, s = s0 + ty*4 + i  (float4 along s)
#pragma unroll
    for (int j = 0; j < 4; ++j) {
        float4 w;
        w.x = acc[0][j]; w.y = acc[1][j]; w.z = acc[2][j]; w.w = acc[3][j];
        *(float4*)&scores[((size_t)(b * CC + tx * 4 + j)) * SS + s0 + ty * 4] = w;
    }
}

// ---------------- Kernel B: in-place softmax over s for each of B*C rows
__global__ __launch_bounds__(256) void softmax_kernel(float* __restrict__ scores)
{
    float* p = scores + (size_t)blockIdx.x * SS;
    const int t = threadIdx.x;
    float4 v[4];
    float m = -3.0e38f;
#pragma unroll
    for (int i = 0; i < 4; ++i) {
        v[i] = *(const float4*)&p[t * 4 + i * 1024];
        m = fmaxf(m, fmaxf(fmaxf(v[i].x, v[i].y), fmaxf(v[i].z, v[i].w)));
    }
#pragma unroll
    for (int off = 1; off < 64; off <<= 1) m = fmaxf(m, __shfl_xor(m, off));
    __shared__ float redm[4];
    __shared__ float reds[4];
    const int wave = t >> 6, lane = t & 63;
    if (lane == 0) redm[wave] = m;
    __syncthreads();
    m = fmaxf(fmaxf(redm[0], redm[1]), fmaxf(redm[2], redm[3]));

    float sum = 0.0f;
#pragma unroll
    for (int i = 0; i < 4; ++i) {
        v[i].x = __expf(v[i].x - m); v[i].y = __expf(v[i].y - m);
        v[i].z = __expf(v[i].z - m); v[i].w = __expf(v[i].w - m);
        sum += (v[i].x + v[i].y) + (v[i].z + v[i].w);
    }
#pragma unroll
    for (int off = 1; off < 64; off <<= 1) sum += __shfl_xor(sum, off);
    if (lane == 0) reds[wave] = sum;
    __syncthreads();
    sum = (reds[0] + reds[1]) + (reds[2] + reds[3]);
    const float inv = 1.0f / sum;
#pragma unroll
    for (int i = 0; i < 4; ++i) {
        v[i].x *= inv; v[i].y *= inv; v[i].z *= inv; v[i].w *= inv;
        *(float4*)&p[t * 4 + i * 1024] = v[i];
    }
}

// ---------------- Kernel C: parts[ks][b][c][h] = sum_{s in quarter ks} factor[b,c,s]*hidden[b,s,h]
// 64(c) x 64(h) tile, 4-way split-K over S for occupancy (grid 16*16*4 = 1024 blocks).
__global__ __launch_bounds__(256) void pool_kernel(
    const float* __restrict__ hidden, const float* __restrict__ factor,
    float* __restrict__ parts)
{
    const int b    = blockIdx.y;
    const int h0   = blockIdx.x * 64;
    const int ks   = blockIdx.z;
    const int sbeg = ks * (SS / 4);
    const int t  = threadIdx.x;
    const int tx = t & 15;   // h-quad
    const int ty = t >> 4;   // c-quad
    const int lr  = t >> 4;
    const int lk4 = (t & 15) * 4;

    __shared__ float fs[64][68]; // [s][c]
    __shared__ float hd[64][68]; // [s][h]

    float acc[4][4];
#pragma unroll
    for (int i = 0; i < 4; ++i)
#pragma unroll
        for (int j = 0; j < 4; ++j) acc[i][j] = 0.0f;

    for (int sc = 0; sc < SS / 4; sc += 64) {
#pragma unroll
        for (int rr = 0; rr < 4; ++rr) {
            const int c = lr + rr * 16;
            const float4 v = *(const float4*)&factor[((size_t)(b * CC + c)) * SS + sbeg + sc + lk4];
            fs[lk4 + 0][c] = v.x; fs[lk4 + 1][c] = v.y;
            fs[lk4 + 2][c] = v.z; fs[lk4 + 3][c] = v.w;
        }
#pragma unroll
        for (int rr = 0; rr < 4; ++rr) {
            const int r = lr + rr * 16;
            *(float4*)&hd[r][lk4] =
                *(const float4*)&hidden[((size_t)b * SS + (size_t)(sbeg + sc + r)) * HH + h0 + lk4];
        }
        __syncthreads();
#pragma unroll 8
        for (int s = 0; s < 64; ++s) {
            const float4 f = *(const float4*)&fs[s][ty * 4];
            const float4 hv = *(const float4*)&hd[s][tx * 4];
            const float fv[4] = {f.x, f.y, f.z, f.w};
            const float hh[4] = {hv.x, hv.y, hv.z, hv.w};
#pragma unroll
            for (int i = 0; i < 4; ++i)
#pragma unroll
                for (int j = 0; j < 4; ++j)
                    acc[i][j] = fmaf(fv[i], hh[j], acc[i][j]);
        }
        __syncthreads();
    }
    float* dst = parts + (size_t)ks * (BB * CC * HH);
#pragma unroll
    for (int i = 0; i < 4; ++i) {
        float4 w;
        w.x = acc[i][0]; w.y = acc[i][1]; w.z = acc[i][2]; w.w = acc[i][3];
        *(float4*)&dst[(size_t)b * (CC * HH) + (size_t)(ty * 4 + i) * HH + h0 + tx * 4] = w;
    }
}

// ---------------- Kernel D: out = sum of 4 split-K partials
__global__ __launch_bounds__(256) void reduce4_kernel(
    const float* __restrict__ parts, float* __restrict__ out)
{
    const int i = blockIdx.x * 256 + threadIdx.x;   // float4 index
    const float4* p = (const float4*)parts;
    const float4 a = p[i];
    const float4 b = p[i + 262144];
    const float4 c = p[i + 524288];
    const float4 d = p[i + 786432];
    float4 r;
    r.x = (a.x + b.x) + (c.x + d.x);
    r.y = (a.y + b.y) + (c.y + d.y);
    r.z = (a.z + b.z) + (c.z + d.z);
    r.w = (a.w + b.w) + (c.w + d.w);
    ((float4*)out)[i] = r;
}

extern "C" void kernel_launch(void* const* d_in, const int* in_sizes, int n_in,
                              void* d_out, int out_size, void* d_ws, size_t ws_size,
                              hipStream_t stream)
{
    const float* hidden = (const float*)d_in[0];   // [16,4096,1024] fp32
    const float* querys = (const float*)d_in[1];   // [64,1024] fp32
    float* out = (float*)d_out;                    // [16, 65536] fp32

    float* scores = (float*)d_ws;                         // B*C*S floats = 16 MiB
    float* parts  = scores + (size_t)BB * CC * SS;        // 4*B*C*H floats = 16 MiB

    scores_kernel<<<dim3(SS / 64, BB), 256, 0, stream>>>(hidden, querys, scores);
    softmax_kernel<<<dim3(BB * CC), 256, 0, stream>>>(scores);
    pool_kernel<<<dim3(HH / 64, BB, 4), 256, 0, stream>>>(hidden, scores, parts);
    reduce4_kernel<<<dim3(1024), 256, 0, stream>>>(parts, out);
}

// Round 2
// 455.613 us; speedup vs baseline: 1.1854x; 1.1854x over previous
//
#include <hip/hip_runtime.h>
#include <math.h>

#define BB 16
#define SS 4096
#define HH 1024
#define CC 64

typedef __attribute__((ext_vector_type(4))) float f32x4;
typedef __attribute__((ext_vector_type(8))) short s16x8;

__device__ __forceinline__ ushort f2bf(float x) {
    union { float f; unsigned u; } un; un.f = x;
    unsigned r = (un.u + 0x7FFFu + ((un.u >> 16) & 1u)) >> 16;
    return (ushort)r;
}
__device__ __forceinline__ float bf2f(ushort h) {
    union { unsigned u; float f; } un; un.u = ((unsigned)h) << 16; return un.f;
}

// ---------------- prep: querys -> hi/lo bf16
__global__ __launch_bounds__(256) void prep_querys_kernel(
    const float* __restrict__ q, ushort* __restrict__ qhi, ushort* __restrict__ qlo)
{
    const int i4 = blockIdx.x * 256 + threadIdx.x;   // float4 index, 16384 total
    const float4 v = ((const float4*)q)[i4];
    ushort4 h, l;
    h.x = f2bf(v.x); l.x = f2bf(v.x - bf2f(h.x));
    h.y = f2bf(v.y); l.y = f2bf(v.y - bf2f(h.y));
    h.z = f2bf(v.z); l.z = f2bf(v.z - bf2f(h.z));
    h.w = f2bf(v.w); l.w = f2bf(v.w - bf2f(h.w));
    ((ushort4*)qhi)[i4] = h;
    ((ushort4*)qlo)[i4] = l;
}

// ---------------- scores[b][c][s] via split-bf16 MFMA: 128s x 64c tile/block
__global__ __launch_bounds__(256) void scores_kernel(
    const float* __restrict__ hidden, const ushort* __restrict__ qhi,
    const ushort* __restrict__ qlo, float* __restrict__ scores)
{
    __shared__ __align__(16) ushort Ahi[128][40];
    __shared__ __align__(16) ushort Alo[128][40];
    __shared__ __align__(16) ushort Bhi[64][40];
    __shared__ __align__(16) ushort Blo[64][40];

    const int b  = blockIdx.y;
    const int s0 = blockIdx.x * 128;
    const int t  = threadIdx.x;
    const int w    = t >> 6;
    const int lane = t & 63;
    const int col  = lane & 15;
    const int quad = lane >> 4;
    const int lr = t >> 3;   // 0..31
    const int lc = t & 7;    // k-col group (4 floats)

    f32x4 acc[2][4];
#pragma unroll
    for (int i = 0; i < 2; ++i)
#pragma unroll
        for (int j = 0; j < 4; ++j) acc[i][j] = (f32x4){0.f, 0.f, 0.f, 0.f};

    const float* hbase = hidden + ((size_t)b * SS + s0) * HH;

    float4 hv[4];
    ushort4 qh[2], ql[2];
#pragma unroll
    for (int p = 0; p < 4; ++p)
        hv[p] = *(const float4*)&hbase[(size_t)(lr + 32 * p) * HH + lc * 4];
#pragma unroll
    for (int p = 0; p < 2; ++p) {
        qh[p] = ((const ushort4*)qhi)[(lr + 32 * p) * 256 + lc];
        ql[p] = ((const ushort4*)qlo)[(lr + 32 * p) * 256 + lc];
    }

    for (int k0 = 0; k0 < HH; k0 += 32) {
        __syncthreads();
#pragma unroll
        for (int p = 0; p < 4; ++p) {
            const int r = lr + 32 * p;
            ushort4 h, l;
            h.x = f2bf(hv[p].x); l.x = f2bf(hv[p].x - bf2f(h.x));
            h.y = f2bf(hv[p].y); l.y = f2bf(hv[p].y - bf2f(h.y));
            h.z = f2bf(hv[p].z); l.z = f2bf(hv[p].z - bf2f(h.z));
            h.w = f2bf(hv[p].w); l.w = f2bf(hv[p].w - bf2f(h.w));
            *(ushort4*)&Ahi[r][lc * 4] = h;
            *(ushort4*)&Alo[r][lc * 4] = l;
        }
#pragma unroll
        for (int p = 0; p < 2; ++p) {
            *(ushort4*)&Bhi[lr + 32 * p][lc * 4] = qh[p];
            *(ushort4*)&Blo[lr + 32 * p][lc * 4] = ql[p];
        }
        __syncthreads();

        if (k0 + 32 < HH) {
            const int kn = k0 + 32;
#pragma unroll
            for (int p = 0; p < 4; ++p)
                hv[p] = *(const float4*)&hbase[(size_t)(lr + 32 * p) * HH + kn + lc * 4];
#pragma unroll
            for (int p = 0; p < 2; ++p) {
                qh[p] = ((const ushort4*)qhi)[(lr + 32 * p) * 256 + kn / 4 + lc];
                ql[p] = ((const ushort4*)qlo)[(lr + 32 * p) * 256 + kn / 4 + lc];
            }
        }

        s16x8 ah[2], al[2], bh[4], bl[4];
#pragma unroll
        for (int mt = 0; mt < 2; ++mt) {
            const int r = w * 32 + mt * 16 + col;
            ah[mt] = *(const s16x8*)&Ahi[r][quad * 8];
            al[mt] = *(const s16x8*)&Alo[r][quad * 8];
        }
#pragma unroll
        for (int nt = 0; nt < 4; ++nt) {
            const int r = nt * 16 + col;
            bh[nt] = *(const s16x8*)&Bhi[r][quad * 8];
            bl[nt] = *(const s16x8*)&Blo[r][quad * 8];
        }
#pragma unroll
        for (int mt = 0; mt < 2; ++mt)
#pragma unroll
            for (int nt = 0; nt < 4; ++nt) {
                acc[mt][nt] = __builtin_amdgcn_mfma_f32_16x16x32_bf16(ah[mt], bh[nt], acc[mt][nt], 0, 0, 0);
                acc[mt][nt] = __builtin_amdgcn_mfma_f32_16x16x32_bf16(ah[mt], bl[nt], acc[mt][nt], 0, 0, 0);
                acc[mt][nt] = __builtin_amdgcn_mfma_f32_16x16x32_bf16(al[mt], bh[nt], acc[mt][nt], 0, 0, 0);
            }
    }

    // C/D: col=lane&15 -> c (within n-tile), row=quad*4+reg -> s (within m-tile)
#pragma unroll
    for (int mt = 0; mt < 2; ++mt)
#pragma unroll
        for (int nt = 0; nt < 4; ++nt) {
            const int c = nt * 16 + col;
            const int s = s0 + w * 32 + mt * 16 + quad * 4;
            *(f32x4*)&scores[((size_t)(b * CC + c)) * SS + s] = acc[mt][nt];
        }
}

// ---------------- softmax over s, writes bf16 factor
__global__ __launch_bounds__(256) void softmax_kernel(
    const float* __restrict__ scores, ushort* __restrict__ factor)
{
    const float* p = scores + (size_t)blockIdx.x * SS;
    ushort* f = factor + (size_t)blockIdx.x * SS;
    const int t = threadIdx.x;
    float4 v[4];
    float m = -3.0e38f;
#pragma unroll
    for (int i = 0; i < 4; ++i) {
        v[i] = *(const float4*)&p[t * 4 + i * 1024];
        m = fmaxf(m, fmaxf(fmaxf(v[i].x, v[i].y), fmaxf(v[i].z, v[i].w)));
    }
#pragma unroll
    for (int off = 1; off < 64; off <<= 1) m = fmaxf(m, __shfl_xor(m, off));
    __shared__ float redm[4];
    __shared__ float reds[4];
    const int wave = t >> 6, lane = t & 63;
    if (lane == 0) redm[wave] = m;
    __syncthreads();
    m = fmaxf(fmaxf(redm[0], redm[1]), fmaxf(redm[2], redm[3]));

    float sum = 0.0f;
#pragma unroll
    for (int i = 0; i < 4; ++i) {
        v[i].x = __expf(v[i].x - m); v[i].y = __expf(v[i].y - m);
        v[i].z = __expf(v[i].z - m); v[i].w = __expf(v[i].w - m);
        sum += (v[i].x + v[i].y) + (v[i].z + v[i].w);
    }
#pragma unroll
    for (int off = 1; off < 64; off <<= 1) sum += __shfl_xor(sum, off);
    if (lane == 0) reds[wave] = sum;
    __syncthreads();
    sum = (reds[0] + reds[1]) + (reds[2] + reds[3]);
    const float inv = 1.0f / sum;
#pragma unroll
    for (int i = 0; i < 4; ++i) {
        ushort4 o;
        o.x = f2bf(v[i].x * inv); o.y = f2bf(v[i].y * inv);
        o.z = f2bf(v[i].z * inv); o.w = f2bf(v[i].w * inv);
        ((ushort4*)f)[t + i * 256] = o;
    }
}

// ---------------- pool: parts[ks][b][c][h] via bf16 MFMA, 64c x 64h tile, split-4 over S
__global__ __launch_bounds__(256) void pool_kernel(
    const float* __restrict__ hidden, const ushort* __restrict__ factor,
    float* __restrict__ parts)
{
    __shared__ __align__(16) ushort Ht[64][72];  // [h][s], s contiguous

    const int b  = blockIdx.y;
    const int h0 = blockIdx.x * 64;
    const int ks = blockIdx.z;
    const int sbeg = ks * (SS / 4);
    const int t = threadIdx.x;
    const int w = t >> 6, lane = t & 63, col = lane & 15, quad = lane >> 4;
    const int hc = t & 15;
    const int sq = t >> 4;   // 0..15

    f32x4 acc[4];
#pragma unroll
    for (int j = 0; j < 4; ++j) acc[j] = (f32x4){0.f, 0.f, 0.f, 0.f};

    const float* hbase = hidden + (size_t)b * SS * HH + h0;
    const ushort* fbase = factor + (size_t)(b * CC + w * 16 + col) * SS + sbeg;

    float v[16];
#pragma unroll
    for (int pp = 0; pp < 2; ++pp)
#pragma unroll
        for (int mm = 0; mm < 4; ++mm)
#pragma unroll
            for (int e = 0; e < 2; ++e)
                v[pp * 8 + mm * 2 + e] =
                    hbase[(size_t)(sbeg + 2 * (sq + 16 * pp) + e) * HH + hc + 16 * mm];

    for (int sc = 0; sc < SS / 4; sc += 64) {
        __syncthreads();
#pragma unroll
        for (int pp = 0; pp < 2; ++pp)
#pragma unroll
            for (int mm = 0; mm < 4; ++mm) {
                unsigned pack = (unsigned)f2bf(v[pp * 8 + mm * 2 + 0]) |
                                ((unsigned)f2bf(v[pp * 8 + mm * 2 + 1]) << 16);
                ((unsigned*)Ht)[(hc + 16 * mm) * 36 + (sq + 16 * pp)] = pack;
            }
        __syncthreads();

        const s16x8 fa0 = *(const s16x8*)&fbase[sc + quad * 8];
        const s16x8 fa1 = *(const s16x8*)&fbase[sc + 32 + quad * 8];

        if (sc + 64 < SS / 4) {
#pragma unroll
            for (int pp = 0; pp < 2; ++pp)
#pragma unroll
                for (int mm = 0; mm < 4; ++mm)
#pragma unroll
                    for (int e = 0; e < 2; ++e)
                        v[pp * 8 + mm * 2 + e] =
                            hbase[(size_t)(sbeg + sc + 64 + 2 * (sq + 16 * pp) + e) * HH + hc + 16 * mm];
        }

#pragma unroll
        for (int ksp = 0; ksp < 2; ++ksp) {
            const s16x8 fa = ksp ? fa1 : fa0;
#pragma unroll
            for (int nt = 0; nt < 4; ++nt) {
                const s16x8 hb = *(const s16x8*)&Ht[nt * 16 + col][ksp * 32 + quad * 8];
                acc[nt] = __builtin_amdgcn_mfma_f32_16x16x32_bf16(fa, hb, acc[nt], 0, 0, 0);
            }
        }
    }

    float* dst = parts + (size_t)ks * (BB * CC * HH) + (size_t)b * (CC * HH);
#pragma unroll
    for (int nt = 0; nt < 4; ++nt) {
        const int h = h0 + nt * 16 + col;
#pragma unroll
        for (int r = 0; r < 4; ++r) {
            const int c = w * 16 + quad * 4 + r;
            dst[(size_t)c * HH + h] = acc[nt][r];
        }
    }
}

// ---------------- final reduce of 4 split-K partials
__global__ __launch_bounds__(256) void reduce4_kernel(
    const float* __restrict__ parts, float* __restrict__ out)
{
    const int i = blockIdx.x * 256 + threadIdx.x;   // float4 index
    const float4* p = (const float4*)parts;
    const float4 a = p[i];
    const float4 b = p[i + 262144];
    const float4 c = p[i + 524288];
    const float4 d = p[i + 786432];
    float4 r;
    r.x = (a.x + b.x) + (c.x + d.x);
    r.y = (a.y + b.y) + (c.y + d.y);
    r.z = (a.z + b.z) + (c.z + d.z);
    r.w = (a.w + b.w) + (c.w + d.w);
    ((float4*)out)[i] = r;
}

extern "C" void kernel_launch(void* const* d_in, const int* in_sizes, int n_in,
                              void* d_out, int out_size, void* d_ws, size_t ws_size,
                              hipStream_t stream)
{
    const float* hidden = (const float*)d_in[0];   // [16,4096,1024] fp32
    const float* querys = (const float*)d_in[1];   // [64,1024] fp32
    float* out = (float*)d_out;

    float*  scores = (float*)d_ws;                           // 16 MiB [0,16M)
    float*  parts  = (float*)d_ws;                           // aliases scores (pool phase)
    ushort* factor = (ushort*)((char*)d_ws + (16u << 20));   // 8 MiB [16M,24M)
    ushort* qhi    = (ushort*)((char*)d_ws + (24u << 20));   // 128 KiB
    ushort* qlo    = qhi + CC * HH;                          // 128 KiB

    prep_querys_kernel<<<dim3(CC * HH / 1024), 256, 0, stream>>>(querys, qhi, qlo);
    scores_kernel<<<dim3(SS / 128, BB), 256, 0, stream>>>(hidden, qhi, qlo, scores);
    softmax_kernel<<<dim3(BB * CC), 256, 0, stream>>>(scores, factor);
    pool_kernel<<<dim3(HH / 64, BB, 4), 256, 0, stream>>>(hidden, factor, parts);
    reduce4_kernel<<<dim3(1024), 256, 0, stream>>>(parts, out);
}